// Round 3
// baseline (356.421 us; speedup 1.0000x reference)
//
#include <hip/hip_runtime.h>
#include <math.h>

// EmformerAttention MI355X — round 8: attention rewritten BARRIER-FREE.
// K and VT MFMA B-fragments are read directly from global (XCD-local L2 via
// block remap) into registers — no LDS staging, no per-tile __syncthreads.
// Only 2 barriers remain (scores->softmax->PV). LDS 53.7->37 KB (4 blk/CU).
// detect_mask merged into conv9 launch; maskprep merged into GEMM launch.
// GEMM structure unchanged from round 7 (m97-class, control).
// U=512 B=16 D=512 H=8 HD=64 R=32 S=16 M=32 -> Q=560 KV=576 N=128

#define NEG_INF_F (-100000000.0f)
#define SCALE_F   (0.125f)

typedef short  short8 __attribute__((ext_vector_type(8)));
typedef float  f32x4  __attribute__((ext_vector_type(4)));
typedef unsigned short u16x4 __attribute__((ext_vector_type(4)));
typedef unsigned short u16x8 __attribute__((ext_vector_type(8)));

__device__ __forceinline__ unsigned short f2b(float f) {
    unsigned int u = __builtin_bit_cast(unsigned int, f);
    u = u + 0x7FFFu + ((u >> 16) & 1u);
    return (unsigned short)(u >> 16);
}
__device__ __forceinline__ float b2f(unsigned short h) {
    unsigned int u = ((unsigned int)h) << 16;
    return __builtin_bit_cast(float, u);
}

// XOR-swizzled index for the score matrix in LDS (ld = 576 shorts).
__device__ __forceinline__ int swzS(int row, int colB) {
    return row * 576 + ((colB ^ ((row & 7) << 4)) >> 1);
}

// ---------------------------------------------------------------------------
// conv9 + mask-dtype detection (blockIdx.y == 9).
__global__ __launch_bounds__(256) void conv9_kernel(
    const float* s0, const float* s1, const float* s2, const float* s3,
    const float* s4, const float* s5, const float* s6, const float* s7,
    const float* s8,
    unsigned short* d0, unsigned short* d1, unsigned short* d2,
    unsigned short* d3, unsigned short* d4, unsigned short* d5,
    unsigned short* d6, unsigned short* d7, unsigned short* d8,
    int n0, int n1, int n2, int n3, int n4, int n5, int n6, int n7, int n8,
    const unsigned int* __restrict__ mask, int nwords, int* __restrict__ flags)
{
    __shared__ int fF, fG;
    const int a = blockIdx.y;
    if (a == 9) {
        if (threadIdx.x == 0) { fF = 0; fG = 0; }
        __syncthreads();
        int lF = 0, lG = 0;
        for (int i = blockIdx.x * 256 + threadIdx.x; i < nwords; i += gridDim.x * 256) {
            unsigned int w = mask[i];
            if (w == 0x3F800000u)      lF = 1;
            else if (w > 1u)           lG = 1;
        }
        if (lF) atomicOr(&fF, 1);
        if (lG) atomicOr(&fG, 1);
        __syncthreads();
        if (threadIdx.x == 0) {
            if (fF) atomicOr(&flags[0], 1);
            if (fG) atomicOr(&flags[1], 1);
        }
        return;
    }
    const float* ss[9] = {s0, s1, s2, s3, s4, s5, s6, s7, s8};
    unsigned short* dd[9] = {d0, d1, d2, d3, d4, d5, d6, d7, d8};
    int nn[9] = {n0, n1, n2, n3, n4, n5, n6, n7, n8};
    const float* s = ss[a];
    unsigned short* d = dd[a];
    const int nq = nn[a] >> 2;
    for (int i = blockIdx.x * 256 + threadIdx.x; i < nq; i += gridDim.x * 256) {
        float4 v = *(const float4*)(s + (size_t)i * 4);
        u16x4 o = {f2b(v.x), f2b(v.y), f2b(v.z), f2b(v.w)};
        *(u16x4*)(d + (size_t)i * 4) = o;
    }
}

// ---------------------------------------------------------------------------
// m97-class bf16 MFMA GEMM (unchanged structure) + maskprep tail blocks.
struct GemmJob {
    const unsigned short *a0, *a1, *a2;   // piecewise A rows
    int rb1, rb2, Mrows;
    const unsigned short *Wt;             // [N][512] bf16 (row = out col)
    const float *bias;
    float *out0, *out1;
    unsigned short *auxU, *auxV;
    const float *pbu, *pbv;
    int mode, clampStart;
    int nBlocks;                          // grid blocks along N
    int base;                             // first linear block id of this job
};

__global__ __launch_bounds__(256) void gemm_mfma3(
    GemmJob J0, GemmJob J1, GemmJob J2,
    const void* __restrict__ maskPtr, const int* __restrict__ flags,
    const int* __restrict__ lengths,
    unsigned short* __restrict__ maskB, unsigned short* __restrict__ padB,
    int maskBase)
{
    __shared__ __attribute__((aligned(16))) unsigned short As[128 * 64];
    __shared__ __attribute__((aligned(16))) unsigned short Ws[128 * 64];

    const int bid = blockIdx.x;
    if (bid >= maskBase) {
        // ---- maskprep tail blocks
        const int mode = flags[0] ? 2 : (flags[1] ? 1 : 0);
        const unsigned short NB = f2b(NEG_INF_F);
        const int nBlk = gridDim.x - maskBase;
        const int stride = nBlk * 256;
        for (int i = (bid - maskBase) * 256 + threadIdx.x; i < 560 * 576; i += stride) {
            bool m;
            if (mode == 1)      m = ((const unsigned char*)maskPtr)[i] != 0;
            else if (mode == 2) m = ((const float*)maskPtr)[i] != 0.f;
            else                m = ((const int*)maskPtr)[i] != 0;
            maskB[i] = m ? NB : (unsigned short)0;
        }
        for (int i = (bid - maskBase) * 256 + threadIdx.x; i < 16 * 576; i += stride) {
            int b = i / 576, k = i - b * 576;
            padB[i] = (k >= 64 + lengths[b]) ? NB : (unsigned short)0;
        }
        return;
    }

    GemmJob J;
    if (bid >= J2.base)      J = J2;
    else if (bid >= J1.base) J = J1;
    else                     J = J0;
    const int rel = bid - J.base;
    const int bn = (rel % J.nBlocks) * 128;
    const int bm = (rel / J.nBlocks) * 128;

    const int tid = threadIdx.x;
    const int w = tid >> 6, lane = tid & 63;
    const int l15 = lane & 15, l4 = lane >> 4;
    const int wm = (w & 1) * 64, wn = (w >> 1) * 64;

    const int lrow  = lane >> 3;
    const int lslot = lane & 7;
    const int swzS16 = (lslot ^ lrow) * 8;     // pre-swizzled source column

    const unsigned short* srcA[4];
    const unsigned short* srcW[4];
    #pragma unroll
    for (int c = 0; c < 4; ++c) {
        const int row = w * 32 + c * 8 + lrow;
        const int r = bm + row;
        const unsigned short* s;
        if (r < J.rb1)      s = J.a0 + (size_t)r * 512;
        else if (r < J.rb2) s = J.a1 + (size_t)(r - J.rb1) * 512;
        else                s = J.a2 + (size_t)(r - J.rb2) * 512;
        srcA[c] = s + swzS16;
        srcW[c] = J.Wt + (size_t)(bn + row) * 512 + swzS16;
    }

    f32x4 acc[4][4];
    #pragma unroll
    for (int i = 0; i < 4; ++i)
        #pragma unroll
        for (int j = 0; j < 4; ++j) acc[i][j] = (f32x4){0.f, 0.f, 0.f, 0.f};

    #define GFRAG(arr, row, kk) \
        (*(const short8*)&arr[(row) * 64 + ((((kk) * 4 + l4) ^ ((row) & 7)) * 8)])

    for (int kt = 0; kt < 8; ++kt) {
        __syncthreads();
        #pragma unroll
        for (int c = 0; c < 4; ++c) {
            __builtin_amdgcn_global_load_lds(
                (const __attribute__((address_space(1))) unsigned int*)(srcA[c] + kt * 64),
                (__attribute__((address_space(3))) unsigned int*)&As[(w * 32 + c * 8) * 64],
                16, 0, 0);
            __builtin_amdgcn_global_load_lds(
                (const __attribute__((address_space(1))) unsigned int*)(srcW[c] + kt * 64),
                (__attribute__((address_space(3))) unsigned int*)&Ws[(w * 32 + c * 8) * 64],
                16, 0, 0);
        }
        __syncthreads();

        short8 bfr[4][2];
        #pragma unroll
        for (int t = 0; t < 4; ++t) {
            const int r = wn + t * 16 + l15;
            bfr[t][0] = GFRAG(Ws, r, 0);
            bfr[t][1] = GFRAG(Ws, r, 1);
        }
        #pragma unroll
        for (int tm = 0; tm < 4; ++tm) {
            const int r = wm + tm * 16 + l15;
            const short8 a0f = GFRAG(As, r, 0);
            const short8 a1f = GFRAG(As, r, 1);
            #pragma unroll
            for (int tn = 0; tn < 4; ++tn) {
                acc[tm][tn] = __builtin_amdgcn_mfma_f32_16x16x32_bf16(
                    a0f, bfr[tn][0], acc[tm][tn], 0, 0, 0);
                acc[tm][tn] = __builtin_amdgcn_mfma_f32_16x16x32_bf16(
                    a1f, bfr[tn][1], acc[tm][tn], 0, 0, 0);
            }
        }
    }
    #undef GFRAG

    #pragma unroll
    for (int tm = 0; tm < 4; ++tm) {
        #pragma unroll
        for (int tn = 0; tn < 4; ++tn) {
            const int col = bn + wn + tn * 16 + l15;
            const float bv = J.bias ? J.bias[col] : 0.f;
            #pragma unroll
            for (int rr = 0; rr < 4; ++rr) {
                const int row = bm + wm + tm * 16 + l4 * 4 + rr;
                if (row >= J.Mrows) continue;
                float v = acc[tm][tn][rr] + bv;
                if (J.mode == 0) {
                    if (row >= J.clampStart) v = fminf(fmaxf(v, -10.f), 10.f);
                    J.out0[(size_t)row * 512 + col] = v;
                } else if (J.mode == 1) {
                    int bb = row & 15, kv = row >> 4;
                    if (col < 512) {
                        J.out0[(size_t)row * 512 + col] = v;
                        int hh = col >> 6, hd = col & 63;
                        J.auxU[(((size_t)(bb * 8 + hh)) * 576 + kv) * 64 + hd] = f2b(v);
                    } else {
                        J.out1[(size_t)row * 512 + (col - 512)] = v;
                        int cc = col - 512, hh = cc >> 6, hd = cc & 63;
                        J.auxV[(((size_t)(bb * 8 + hh)) * 64 + hd) * 576 + kv] = f2b(v);
                    }
                } else if (J.mode == 2) {
                    int q = row >> 4, bb = row & 15, hh = col >> 6, hd = col & 63;
                    size_t base = (((size_t)(bb * 8 + hh)) * 576 + q) * 64 + hd;
                    J.auxU[base] = f2b((v + J.pbu[col]) * SCALE_F);
                    J.auxV[base] = f2b((v + J.pbv[col]) * SCALE_F);
                } else {
                    int hh = col >> 6, hd = col & 63;
                    J.auxU[((size_t)hh * 1023 + row) * 64 + hd] = f2b(v);
                }
            }
        }
    }
}

// ---------------------------------------------------------------------------
// MFMA attention v7: barrier-free scores/PV. K & VT fragments direct from
// global (XCD-local L2); sc in LDS (XOR-swizzled); 2 barriers total.
// LDS ~37 KB -> 4 blocks/CU (16 waves/CU).
__global__ __launch_bounds__(256) void attn_mfma_kernel(
    const unsigned short* __restrict__ Qu_g,  // [n][576][64], pre-scaled
    const unsigned short* __restrict__ Qv_g,  // [n][576][64], pre-scaled
    const unsigned short* __restrict__ K_g,   // [n][576][64]
    const unsigned short* __restrict__ VT_g,  // [n][64][576]
    const unsigned short* __restrict__ P_g,   // [8][1023][64]
    const unsigned short* __restrict__ maskBias, // [560][576] bf16
    const unsigned short* __restrict__ padBias,  // [16][576] bf16
    unsigned short* __restrict__ attnT)       // bf16
{
    __shared__ __attribute__((aligned(16))) unsigned short sc[32 * 576];
    __shared__ float rowv[32];

    // XCD-aware remap (2304 = 8 x 288, bijective): all 18 blocks sharing one
    // n land on a single XCD -> K/VT served from XCD-local L2.
    const int bid = blockIdx.y * 18 + blockIdx.x;
    const int workid = (bid & 7) * 288 + (bid >> 3);
    const int n = workid / 18;
    const int qt = workid - n * 18;

    const int b = n >> 3, h = n & 7;
    const int q0 = qt * 32;
    const int tid = threadIdx.x;
    const int w = tid >> 6, lane = tid & 63;
    const int l15 = lane & 15, l4 = lane >> 4;
    const int mT = (w >> 1) * 16;
    const int c0 = (w & 1) * 32;
    const int t0base = 16 - mT + c0;
    const bool hasBand = (qt >= 1 && qt <= 16);
    const int pbq = 512 - q0;

    const unsigned short* Kn  = K_g  + (size_t)n * 576 * 64;
    const unsigned short* VTn = VT_g + (size_t)n * 64 * 576;
    const unsigned short* Ph  = P_g  + (size_t)h * 1023 * 64;

    short8 quf[2], qvf[2];
    {
        size_t rb = ((size_t)n * 576 + q0 + mT + l15) * 64;
        quf[0] = *(const short8*)&Qu_g[rb + l4 * 8];
        quf[1] = *(const short8*)&Qu_g[rb + 32 + l4 * 8];
        qvf[0] = *(const short8*)&Qv_g[rb + l4 * 8];
        qvf[1] = *(const short8*)&Qv_g[rb + 32 + l4 * 8];
    }

    // ================= scores (NO barriers) =================
    for (int kt = 0; kt < 9; ++kt) {
        const bool doBand = hasBand && (kt >= 1);
        short8 bnd00, bnd01, bnd10, bnd11, bnd20, bnd21;
        if (doBand) {
            const int pbase = pbq + (kt - 1) * 64 + t0base + l15;
            int p0 = pbase;       p0 = p0 < 0 ? 0 : (p0 > 1022 ? 1022 : p0);
            int p1 = pbase + 16;  p1 = p1 < 0 ? 0 : (p1 > 1022 ? 1022 : p1);
            int p2 = pbase + 32;  p2 = p2 < 0 ? 0 : (p2 > 1022 ? 1022 : p2);
            bnd00 = *(const short8*)&Ph[(size_t)p0 * 64 + l4 * 8];
            bnd01 = *(const short8*)&Ph[(size_t)p0 * 64 + 32 + l4 * 8];
            bnd10 = *(const short8*)&Ph[(size_t)p1 * 64 + l4 * 8];
            bnd11 = *(const short8*)&Ph[(size_t)p1 * 64 + 32 + l4 * 8];
            bnd20 = *(const short8*)&Ph[(size_t)p2 * 64 + l4 * 8];
            bnd21 = *(const short8*)&Ph[(size_t)p2 * 64 + 32 + l4 * 8];
        }
        __builtin_amdgcn_s_setprio(1);
        #pragma unroll
        for (int s = 0; s < 2; ++s) {
            const int n0 = c0 + s * 16;
            // K B-fragment direct from L2: 16 dense 128B rows per fragment.
            const unsigned short* kp = Kn + (size_t)(kt * 64 + n0 + l15) * 64;
            short8 b0 = *(const short8*)&kp[l4 * 8];
            short8 b1 = *(const short8*)&kp[32 + l4 * 8];
            f32x4 acc = {0.f, 0.f, 0.f, 0.f};
            acc = __builtin_amdgcn_mfma_f32_16x16x32_bf16(quf[0], b0, acc, 0, 0, 0);
            acc = __builtin_amdgcn_mfma_f32_16x16x32_bf16(quf[1], b1, acc, 0, 0, 0);
            const int col = kt * 64 + n0 + l15;
            #pragma unroll
            for (int r = 0; r < 4; ++r)
                sc[swzS(mT + l4 * 4 + r, col * 2)] = f2b(acc[r]);
        }
        if (doBand) {
            // Band add region is provably within this wave's own (mT,c0)
            // tile; same-wave LDS ops are ordered -> no barrier needed.
            #pragma unroll
            for (int s = 0; s < 3; ++s) {
                short8 ba = (s == 0) ? bnd00 : ((s == 1) ? bnd10 : bnd20);
                short8 bb = (s == 0) ? bnd01 : ((s == 1) ? bnd11 : bnd21);
                f32x4 acc = {0.f, 0.f, 0.f, 0.f};
                acc = __builtin_amdgcn_mfma_f32_16x16x32_bf16(qvf[0], ba, acc, 0, 0, 0);
                acc = __builtin_amdgcn_mfma_f32_16x16x32_bf16(qvf[1], bb, acc, 0, 0, 0);
                const int tl = t0base + s * 16 + l15;
                #pragma unroll
                for (int r = 0; r < 4; ++r) {
                    const int du = mT + l4 * 4 + r;
                    const int dj = tl - 31 + du;
                    if (dj >= c0 && dj < c0 + 32) {
                        const int ix = swzS(du, (kt * 64 + dj) * 2);
                        sc[ix] = f2b(b2f(sc[ix]) + acc[r]);
                    }
                }
            }
        }
        __builtin_amdgcn_s_setprio(0);
    }
    __syncthreads();                           // all scores visible

    // ============ softmax (8 consecutive lanes per row; shfl reduce) ========
    {
        const int row = tid >> 3, seg = tid & 7;
        const int q = q0 + row;
        const int qc = q < 560 ? q : 559;      // garbage rows: harmless bias
        const unsigned short* mb  = maskBias + (size_t)qc * 576 + seg * 72;
        const unsigned short* pbb = padBias + (size_t)b * 576 + seg * 72;
        float mx = -3.0e38f;
        #pragma unroll
        for (int ci = 0; ci < 9; ++ci) {
            u16x8 sv = *(const u16x8*)&sc[swzS(row, seg * 144 + ci * 16)];
            u16x8 mv = *(const u16x8*)&mb[ci * 8];
            u16x8 pv = *(const u16x8*)&pbb[ci * 8];
            #pragma unroll
            for (int j = 0; j < 8; ++j)
                mx = fmaxf(mx, b2f(sv[j]) + b2f(mv[j]) + b2f(pv[j]));
        }
        mx = fmaxf(mx, __shfl_xor(mx, 1));
        mx = fmaxf(mx, __shfl_xor(mx, 2));
        mx = fmaxf(mx, __shfl_xor(mx, 4));
        float lsum = 0.f;
        #pragma unroll
        for (int ci = 0; ci < 9; ++ci) {
            const int ix = swzS(row, seg * 144 + ci * 16);
            u16x8 sv = *(const u16x8*)&sc[ix];
            u16x8 mv = *(const u16x8*)&mb[ci * 8];
            u16x8 pv = *(const u16x8*)&pbb[ci * 8];
            u16x8 ev;
            #pragma unroll
            for (int j = 0; j < 8; ++j) {
                float e = __expf(b2f(sv[j]) + b2f(mv[j]) + b2f(pv[j]) - mx);
                ev[j] = f2b(e); lsum += e;
            }
            *(u16x8*)&sc[ix] = ev;
        }
        lsum += __shfl_xor(lsum, 1);
        lsum += __shfl_xor(lsum, 2);
        lsum += __shfl_xor(lsum, 4);
        if (seg == 0) rowv[row] = 1.f / lsum;
    }
    __syncthreads();                           // P + rowv visible

    // ================= PV (NO barriers; VT direct from L2) =================
    f32x4 oacc0 = {0.f, 0.f, 0.f, 0.f}, oacc1 = {0.f, 0.f, 0.f, 0.f};
    for (int kt = 0; kt < 9; ++kt) {
        const unsigned short* vp0 = VTn + (size_t)(c0 + l15) * 576 + kt * 64;
        const unsigned short* vp1 = VTn + (size_t)(c0 + 16 + l15) * 576 + kt * 64;
        short8 b00 = *(const short8*)&vp0[l4 * 8];
        short8 b01 = *(const short8*)&vp0[32 + l4 * 8];
        short8 b10 = *(const short8*)&vp1[l4 * 8];
        short8 b11 = *(const short8*)&vp1[32 + l4 * 8];
        short8 af0 = *(const short8*)&sc[swzS(mT + l15, kt * 128 + l4 * 16)];
        short8 af1 = *(const short8*)&sc[swzS(mT + l15, kt * 128 + 64 + l4 * 16)];
        __builtin_amdgcn_s_setprio(1);
        oacc0 = __builtin_amdgcn_mfma_f32_16x16x32_bf16(af0, b00, oacc0, 0, 0, 0);
        oacc0 = __builtin_amdgcn_mfma_f32_16x16x32_bf16(af1, b01, oacc0, 0, 0, 0);
        oacc1 = __builtin_amdgcn_mfma_f32_16x16x32_bf16(af0, b10, oacc1, 0, 0, 0);
        oacc1 = __builtin_amdgcn_mfma_f32_16x16x32_bf16(af1, b11, oacc1, 0, 0, 0);
        __builtin_amdgcn_s_setprio(0);
    }

    // ---- epilogue -> attnT bf16
    #pragma unroll
    for (int s = 0; s < 2; ++s) {
        const f32x4 oa = s ? oacc1 : oacc0;
        const int n0 = c0 + s * 16;
        #pragma unroll
        for (int r = 0; r < 4; ++r) {
            const int row = mT + l4 * 4 + r, q = q0 + row;
            if (q < 560)
                attnT[((size_t)q * 16 + b) * 512 + h * 64 + n0 + l15] =
                    f2b(oa[r] * rowv[row]);
        }
    }
}

// ---------------------------------------------------------------------------
extern "C" void kernel_launch(void* const* d_in, const int* in_sizes, int n_in,
                              void* d_out, int out_size, void* d_ws, size_t ws_size,
                              hipStream_t stream) {
    const float* utt     = (const float*)d_in[0];
    const int*   lengths = (const int*)d_in[1];
    const float* rc      = (const float*)d_in[2];
    const float* summ    = (const float*)d_in[3];
    const float* mem     = (const float*)d_in[4];
    const void*  mask    = d_in[5];
    const float* pos_emb = (const float*)d_in[6];
    const float* Wq      = (const float*)d_in[7];
    const float* bq      = (const float*)d_in[8];
    const float* Wkv     = (const float*)d_in[9];
    const float* bkv     = (const float*)d_in[10];
    const float* Wo      = (const float*)d_in[11];
    const float* bo      = (const float*)d_in[12];
    const float* Wpos    = (const float*)d_in[13];
    const float* pbu     = (const float*)d_in[14];
    const float* pbv     = (const float*)d_in[15];

    float* out = (float*)d_out;
    float* out0   = out;
    float* keyOut = out + 4587520;
    float* valOut = out + 9306112;

    int* flags = (int*)d_ws;
    unsigned short* U = (unsigned short*)d_ws + 64;
    unsigned short* utt_bf  = U;
    unsigned short* rc_bf   = utt_bf  + 4194304;
    unsigned short* summ_bf = rc_bf   + 262144;
    unsigned short* mem_bf  = summ_bf + 131072;
    unsigned short* pose_bf = mem_bf  + 262144;
    unsigned short* wq_bf   = pose_bf + 523776;
    unsigned short* wkv_bf  = wq_bf   + 262144;
    unsigned short* wo_bf   = wkv_bf  + 524288;
    unsigned short* wpos_bf = wo_bf   + 262144;
    unsigned short* Qu_bf   = wpos_bf + 262144;
    unsigned short* Qv_bf   = Qu_bf   + 4718592;
    unsigned short* K_bf    = Qv_bf   + 4718592;
    unsigned short* VT_bf   = K_bf    + 4718592;
    unsigned short* posW_bf = VT_bf   + 4718592;
    unsigned short* attnT_bf= posW_bf + 523776;
    unsigned short* maskB   = attnT_bf + 4587520;   // 560*576 = 322560
    unsigned short* padB    = maskB + 322560;       // 16*576  = 9216

    hipMemsetAsync(flags, 0, 2 * sizeof(int), stream);

    conv9_kernel<<<dim3(1024, 10), 256, 0, stream>>>(
        utt, rc, summ, mem, pos_emb, Wq, Wkv, Wo, Wpos,
        utt_bf, rc_bf, summ_bf, mem_bf, pose_bf, wq_bf, wkv_bf, wo_bf, wpos_bf,
        4194304, 262144, 131072, 262144, 523776, 262144, 524288, 262144, 262144,
        (const unsigned int*)mask, (560 * 576) / 4, flags);

    // ---- merged Q + KV + pos GEMMs + maskprep tail: 280+576+32+64 = 952 blk
    GemmJob jq;
    jq.a0 = rc_bf; jq.a1 = utt_bf; jq.a2 = summ_bf;
    jq.rb1 = 512; jq.rb2 = 8704; jq.Mrows = 8960;
    jq.Wt = wq_bf; jq.bias = bq;
    jq.out0 = nullptr; jq.out1 = nullptr;
    jq.auxU = Qu_bf; jq.auxV = Qv_bf;
    jq.pbu = pbu; jq.pbv = pbv;
    jq.mode = 2; jq.clampStart = 0; jq.nBlocks = 4; jq.base = 0;

    GemmJob jkv;
    jkv.a0 = mem_bf; jkv.a1 = rc_bf; jkv.a2 = utt_bf;
    jkv.rb1 = 512; jkv.rb2 = 1024; jkv.Mrows = 9216;
    jkv.Wt = wkv_bf; jkv.bias = bkv;
    jkv.out0 = keyOut; jkv.out1 = valOut;
    jkv.auxU = K_bf; jkv.auxV = VT_bf;
    jkv.pbu = nullptr; jkv.pbv = nullptr;
    jkv.mode = 1; jkv.clampStart = 0; jkv.nBlocks = 8; jkv.base = 280;

    GemmJob jp;
    jp.a0 = pose_bf; jp.a1 = pose_bf; jp.a2 = pose_bf;
    jp.rb1 = 1 << 30; jp.rb2 = 1 << 30; jp.Mrows = 1023;
    jp.Wt = wpos_bf; jp.bias = nullptr;
    jp.out0 = nullptr; jp.out1 = nullptr;
    jp.auxU = posW_bf; jp.auxV = nullptr;
    jp.pbu = nullptr; jp.pbv = nullptr;
    jp.mode = 3; jp.clampStart = 0; jp.nBlocks = 4; jp.base = 856;

    gemm_mfma3<<<952, 256, 0, stream>>>(jq, jkv, jp,
        mask, flags, lengths, maskB, padB, 888);

    attn_mfma_kernel<<<dim3(18, 128), 256, 0, stream>>>(
        Qu_bf, Qv_bf, K_bf, VT_bf, posW_bf, maskB, padB, attnT_bf);

    // ---- out-projection (single job)
    GemmJob jo;
    jo.a0 = attnT_bf; jo.a1 = attnT_bf; jo.a2 = attnT_bf;
    jo.rb1 = 1 << 30; jo.rb2 = 1 << 30; jo.Mrows = 8960;
    jo.Wt = wo_bf; jo.bias = bo;
    jo.out0 = out0; jo.out1 = nullptr;
    jo.auxU = nullptr; jo.auxV = nullptr;
    jo.pbu = nullptr; jo.pbv = nullptr;
    jo.mode = 0; jo.clampStart = 8704; jo.nBlocks = 4; jo.base = 0;

    GemmJob jdummy = jo;
    jdummy.base = 1 << 30;

    gemm_mfma3<<<280, 256, 0, stream>>>(jo, jdummy, jdummy,
        mask, flags, lengths, maskB, padB, 1 << 30);
}

// Round 6
// 303.323 us; speedup vs baseline: 1.1751x; 1.1751x over previous
//
#include <hip/hip_runtime.h>
#include <math.h>

// EmformerAttention MI355X — round 9b (retry; previous round was an infra
// failure, kernel never ran): r6 staged double-buffered attn + drain-free
// lgkmcnt-only barriers + log2-domain softmax (v_exp_f32 inline asm).
// U=512 B=16 D=512 H=8 HD=64 R=32 S=16 M=32 -> Q=560 KV=576 N=128

#define NEG_INF_F (-100000000.0f)
#define SCALE_F   (0.125f)
#define LOG2E_F   (1.44269504f)

typedef short  short8 __attribute__((ext_vector_type(8)));
typedef float  f32x4  __attribute__((ext_vector_type(4)));
typedef unsigned short u16x4 __attribute__((ext_vector_type(4)));
typedef unsigned short u16x8 __attribute__((ext_vector_type(8)));

__device__ __forceinline__ unsigned short f2b(float f) {
    unsigned int u = __builtin_bit_cast(unsigned int, f);
    u = u + 0x7FFFu + ((u >> 16) & 1u);
    return (unsigned short)(u >> 16);
}
__device__ __forceinline__ float b2f(unsigned short h) {
    unsigned int u = ((unsigned int)h) << 16;
    return __builtin_bit_cast(float, u);
}

// 2^x via the native transcendental unit (avoids glibc __exp2f macro clash).
__device__ __forceinline__ float exp2_fast(float x) {
    float r;
    asm("v_exp_f32 %0, %1" : "=v"(r) : "v"(x));
    return r;
}

// Workgroup barrier WITHOUT the vmcnt(0) drain: LDS ops are ordered
// (lgkmcnt), register-destined global loads may stay in flight.
__device__ __forceinline__ void barrier_lg() {
    asm volatile("s_waitcnt lgkmcnt(0)\n\ts_barrier" ::: "memory");
}

// XOR-swizzled LDS indices (colB = byte column; same involution both sides).
__device__ __forceinline__ int swzK(int row, int colB) {   // tile ld = 64 shorts
    return row * 64 + ((colB ^ ((row & 7) << 4)) >> 1);
}
__device__ __forceinline__ int swzS(int row, int colB) {   // sc ld = 576 shorts
    return row * 576 + ((colB ^ ((row & 7) << 4)) >> 1);
}

// ---------------------------------------------------------------------------
// conv9 + mask-dtype detection (blockIdx.y == 9).
__global__ __launch_bounds__(256) void conv9_kernel(
    const float* s0, const float* s1, const float* s2, const float* s3,
    const float* s4, const float* s5, const float* s6, const float* s7,
    const float* s8,
    unsigned short* d0, unsigned short* d1, unsigned short* d2,
    unsigned short* d3, unsigned short* d4, unsigned short* d5,
    unsigned short* d6, unsigned short* d7, unsigned short* d8,
    int n0, int n1, int n2, int n3, int n4, int n5, int n6, int n7, int n8,
    const unsigned int* __restrict__ mask, int nwords, int* __restrict__ flags)
{
    __shared__ int fF, fG;
    const int a = blockIdx.y;
    if (a == 9) {
        if (threadIdx.x == 0) { fF = 0; fG = 0; }
        __syncthreads();
        int lF = 0, lG = 0;
        for (int i = blockIdx.x * 256 + threadIdx.x; i < nwords; i += gridDim.x * 256) {
            unsigned int w = mask[i];
            if (w == 0x3F800000u)      lF = 1;
            else if (w > 1u)           lG = 1;
        }
        if (lF) atomicOr(&fF, 1);
        if (lG) atomicOr(&fG, 1);
        __syncthreads();
        if (threadIdx.x == 0) {
            if (fF) atomicOr(&flags[0], 1);
            if (fG) atomicOr(&flags[1], 1);
        }
        return;
    }
    const float* ss[9] = {s0, s1, s2, s3, s4, s5, s6, s7, s8};
    unsigned short* dd[9] = {d0, d1, d2, d3, d4, d5, d6, d7, d8};
    int nn[9] = {n0, n1, n2, n3, n4, n5, n6, n7, n8};
    const float* s = ss[a];
    unsigned short* d = dd[a];
    const int nq = nn[a] >> 2;
    for (int i = blockIdx.x * 256 + threadIdx.x; i < nq; i += gridDim.x * 256) {
        float4 v = *(const float4*)(s + (size_t)i * 4);
        u16x4 o = {f2b(v.x), f2b(v.y), f2b(v.z), f2b(v.w)};
        *(u16x4*)(d + (size_t)i * 4) = o;
    }
}

// ---------------------------------------------------------------------------
// m97-class bf16 MFMA GEMM (unchanged structure) + maskprep tail blocks.
struct GemmJob {
    const unsigned short *a0, *a1, *a2;   // piecewise A rows
    int rb1, rb2, Mrows;
    const unsigned short *Wt;             // [N][512] bf16 (row = out col)
    const float *bias;
    float *out0, *out1;
    unsigned short *auxU, *auxV;
    const float *pbu, *pbv;
    int mode, clampStart;
    int nBlocks;                          // grid blocks along N
    int base;                             // first linear block id of this job
};

__global__ __launch_bounds__(256) void gemm_mfma3(
    GemmJob J0, GemmJob J1, GemmJob J2,
    const void* __restrict__ maskPtr, const int* __restrict__ flags,
    const int* __restrict__ lengths,
    unsigned short* __restrict__ maskB, unsigned short* __restrict__ padB,
    int maskBase)
{
    __shared__ __attribute__((aligned(16))) unsigned short As[128 * 64];
    __shared__ __attribute__((aligned(16))) unsigned short Ws[128 * 64];

    const int bid = blockIdx.x;
    if (bid >= maskBase) {
        const int mode = flags[0] ? 2 : (flags[1] ? 1 : 0);
        const unsigned short NB = f2b(NEG_INF_F);
        const int nBlk = gridDim.x - maskBase;
        const int stride = nBlk * 256;
        for (int i = (bid - maskBase) * 256 + threadIdx.x; i < 560 * 576; i += stride) {
            bool m;
            if (mode == 1)      m = ((const unsigned char*)maskPtr)[i] != 0;
            else if (mode == 2) m = ((const float*)maskPtr)[i] != 0.f;
            else                m = ((const int*)maskPtr)[i] != 0;
            maskB[i] = m ? NB : (unsigned short)0;
        }
        for (int i = (bid - maskBase) * 256 + threadIdx.x; i < 16 * 576; i += stride) {
            int b = i / 576, k = i - b * 576;
            padB[i] = (k >= 64 + lengths[b]) ? NB : (unsigned short)0;
        }
        return;
    }

    GemmJob J;
    if (bid >= J2.base)      J = J2;
    else if (bid >= J1.base) J = J1;
    else                     J = J0;
    const int rel = bid - J.base;
    const int bn = (rel % J.nBlocks) * 128;
    const int bm = (rel / J.nBlocks) * 128;

    const int tid = threadIdx.x;
    const int w = tid >> 6, lane = tid & 63;
    const int l15 = lane & 15, l4 = lane >> 4;
    const int wm = (w & 1) * 64, wn = (w >> 1) * 64;

    const int lrow  = lane >> 3;
    const int lslot = lane & 7;
    const int swzS16 = (lslot ^ lrow) * 8;     // pre-swizzled source column

    const unsigned short* srcA[4];
    const unsigned short* srcW[4];
    #pragma unroll
    for (int c = 0; c < 4; ++c) {
        const int row = w * 32 + c * 8 + lrow;
        const int r = bm + row;
        const unsigned short* s;
        if (r < J.rb1)      s = J.a0 + (size_t)r * 512;
        else if (r < J.rb2) s = J.a1 + (size_t)(r - J.rb1) * 512;
        else                s = J.a2 + (size_t)(r - J.rb2) * 512;
        srcA[c] = s + swzS16;
        srcW[c] = J.Wt + (size_t)(bn + row) * 512 + swzS16;
    }

    f32x4 acc[4][4];
    #pragma unroll
    for (int i = 0; i < 4; ++i)
        #pragma unroll
        for (int j = 0; j < 4; ++j) acc[i][j] = (f32x4){0.f, 0.f, 0.f, 0.f};

    #define GFRAG(arr, row, kk) \
        (*(const short8*)&arr[(row) * 64 + ((((kk) * 4 + l4) ^ ((row) & 7)) * 8)])

    for (int kt = 0; kt < 8; ++kt) {
        __syncthreads();
        #pragma unroll
        for (int c = 0; c < 4; ++c) {
            __builtin_amdgcn_global_load_lds(
                (const __attribute__((address_space(1))) unsigned int*)(srcA[c] + kt * 64),
                (__attribute__((address_space(3))) unsigned int*)&As[(w * 32 + c * 8) * 64],
                16, 0, 0);
            __builtin_amdgcn_global_load_lds(
                (const __attribute__((address_space(1))) unsigned int*)(srcW[c] + kt * 64),
                (__attribute__((address_space(3))) unsigned int*)&Ws[(w * 32 + c * 8) * 64],
                16, 0, 0);
        }
        __syncthreads();

        short8 bfr[4][2];
        #pragma unroll
        for (int t = 0; t < 4; ++t) {
            const int r = wn + t * 16 + l15;
            bfr[t][0] = GFRAG(Ws, r, 0);
            bfr[t][1] = GFRAG(Ws, r, 1);
        }
        #pragma unroll
        for (int tm = 0; tm < 4; ++tm) {
            const int r = wm + tm * 16 + l15;
            const short8 a0f = GFRAG(As, r, 0);
            const short8 a1f = GFRAG(As, r, 1);
            #pragma unroll
            for (int tn = 0; tn < 4; ++tn) {
                acc[tm][tn] = __builtin_amdgcn_mfma_f32_16x16x32_bf16(
                    a0f, bfr[tn][0], acc[tm][tn], 0, 0, 0);
                acc[tm][tn] = __builtin_amdgcn_mfma_f32_16x16x32_bf16(
                    a1f, bfr[tn][1], acc[tm][tn], 0, 0, 0);
            }
        }
    }
    #undef GFRAG

    #pragma unroll
    for (int tm = 0; tm < 4; ++tm) {
        #pragma unroll
        for (int tn = 0; tn < 4; ++tn) {
            const int col = bn + wn + tn * 16 + l15;
            const float bv = J.bias ? J.bias[col] : 0.f;
            #pragma unroll
            for (int rr = 0; rr < 4; ++rr) {
                const int row = bm + wm + tm * 16 + l4 * 4 + rr;
                if (row >= J.Mrows) continue;
                float v = acc[tm][tn][rr] + bv;
                if (J.mode == 0) {
                    if (row >= J.clampStart) v = fminf(fmaxf(v, -10.f), 10.f);
                    J.out0[(size_t)row * 512 + col] = v;
                } else if (J.mode == 1) {
                    int bb = row & 15, kv = row >> 4;
                    if (col < 512) {
                        J.out0[(size_t)row * 512 + col] = v;
                        int hh = col >> 6, hd = col & 63;
                        J.auxU[(((size_t)(bb * 8 + hh)) * 576 + kv) * 64 + hd] = f2b(v);
                    } else {
                        J.out1[(size_t)row * 512 + (col - 512)] = v;
                        int cc = col - 512, hh = cc >> 6, hd = cc & 63;
                        J.auxV[(((size_t)(bb * 8 + hh)) * 64 + hd) * 576 + kv] = f2b(v);
                    }
                } else if (J.mode == 2) {
                    // log2-domain: fold SCALE * log2(e) into Qu AND Qv.
                    int q = row >> 4, bb = row & 15, hh = col >> 6, hd = col & 63;
                    size_t base = (((size_t)(bb * 8 + hh)) * 576 + q) * 64 + hd;
                    J.auxU[base] = f2b((v + J.pbu[col]) * (SCALE_F * LOG2E_F));
                    J.auxV[base] = f2b((v + J.pbv[col]) * (SCALE_F * LOG2E_F));
                } else {
                    int hh = col >> 6, hd = col & 63;
                    J.auxU[((size_t)hh * 1023 + row) * 64 + hd] = f2b(v);
                }
            }
        }
    }
}

// ---------------------------------------------------------------------------
// MFMA attention v8: r6 staged double-buffered pipeline + drain-free barriers
// (lgkmcnt-only) + log2-domain softmax. LDS 53.4 KB -> 3 blocks/CU.
__global__ __launch_bounds__(256) void attn_mfma_kernel(
    const unsigned short* __restrict__ Qu_g,  // [n][576][64], *SCALE*log2e
    const unsigned short* __restrict__ Qv_g,  // [n][576][64], *SCALE*log2e
    const unsigned short* __restrict__ K_g,   // [n][576][64]
    const unsigned short* __restrict__ VT_g,  // [n][64][576]
    const unsigned short* __restrict__ P_g,   // [8][1023][64]
    const unsigned short* __restrict__ maskBias, // [560][576] bf16
    const unsigned short* __restrict__ padBias,  // [16][576] bf16
    unsigned short* __restrict__ attnT)       // bf16
{
    __shared__ __attribute__((aligned(16))) unsigned short sc[32 * 576];
    __shared__ __attribute__((aligned(16))) unsigned short stg[2 * 4096];
    __shared__ float rowv[32];

    // XCD-aware remap (2304 = 8 x 288, bijective).
    const int bid = blockIdx.y * 18 + blockIdx.x;
    const int workid = (bid & 7) * 288 + (bid >> 3);
    const int n = workid / 18;
    const int qt = workid - n * 18;

    const int b = n >> 3, h = n & 7;
    const int q0 = qt * 32;
    const int tid = threadIdx.x;
    const int w = tid >> 6, lane = tid & 63;
    const int l15 = lane & 15, l4 = lane >> 4;
    const int mT = (w >> 1) * 16;
    const int c0 = (w & 1) * 32;
    const int t0base = 16 - mT + c0;
    const bool hasBand = (qt >= 1 && qt <= 16);
    const int pbq = 512 - q0;

    const unsigned short* Kn  = K_g  + (size_t)n * 576 * 64;
    const unsigned short* VTn = VT_g + (size_t)n * 64 * 576;
    const unsigned short* Ph  = P_g  + (size_t)h * 1023 * 64;

    const int srow  = tid >> 3;            // 0..31
    const int sIdx  = (tid & 7) * 8;       // short col within row
    const int scolB = sIdx * 2;            // byte col

    // ---- prologue: stage K tile 0 into buf0
    {
        u16x8 a = *(const u16x8*)&Kn[(size_t)srow * 64 + sIdx];
        u16x8 c = *(const u16x8*)&Kn[(size_t)(srow + 32) * 64 + sIdx];
        *(u16x8*)&stg[swzK(srow, scolB)] = a;
        *(u16x8*)&stg[swzK(srow + 32, scolB)] = c;
    }

    short8 quf[2], qvf[2];
    {
        size_t rb = ((size_t)n * 576 + q0 + mT + l15) * 64;
        quf[0] = *(const short8*)&Qu_g[rb + l4 * 8];
        quf[1] = *(const short8*)&Qu_g[rb + 32 + l4 * 8];
        qvf[0] = *(const short8*)&Qv_g[rb + l4 * 8];
        qvf[1] = *(const short8*)&Qv_g[rb + 32 + l4 * 8];
    }

    // ================= scores (1 drain-free barrier per K-tile) ============
    int cur = 0;
    for (int kt = 0; kt < 9; ++kt) {
        // prefetch next K tile into REGISTERS (stays in flight across barrier)
        u16x8 kna, knb;
        if (kt < 8) {
            kna = *(const u16x8*)&Kn[(size_t)((kt + 1) * 64 + srow) * 64 + sIdx];
            knb = *(const u16x8*)&Kn[(size_t)((kt + 1) * 64 + srow + 32) * 64 + sIdx];
        }
        const bool doBand = hasBand && (kt >= 1);
        short8 bnd00, bnd01, bnd10, bnd11, bnd20, bnd21;
        if (doBand) {
            const int pbase = pbq + (kt - 1) * 64 + t0base + l15;
            int p0 = pbase;       p0 = p0 < 0 ? 0 : (p0 > 1022 ? 1022 : p0);
            int p1 = pbase + 16;  p1 = p1 < 0 ? 0 : (p1 > 1022 ? 1022 : p1);
            int p2 = pbase + 32;  p2 = p2 < 0 ? 0 : (p2 > 1022 ? 1022 : p2);
            bnd00 = *(const short8*)&Ph[(size_t)p0 * 64 + l4 * 8];
            bnd01 = *(const short8*)&Ph[(size_t)p0 * 64 + 32 + l4 * 8];
            bnd10 = *(const short8*)&Ph[(size_t)p1 * 64 + l4 * 8];
            bnd11 = *(const short8*)&Ph[(size_t)p1 * 64 + 32 + l4 * 8];
            bnd20 = *(const short8*)&Ph[(size_t)p2 * 64 + l4 * 8];
            bnd21 = *(const short8*)&Ph[(size_t)p2 * 64 + 32 + l4 * 8];
        }
        barrier_lg();                          // buf[cur] ready (no vmcnt drain)
        unsigned short* buf = stg + cur * 4096;
        __builtin_amdgcn_s_setprio(1);
        #pragma unroll
        for (int s = 0; s < 2; ++s) {
            const int n0 = c0 + s * 16;
            f32x4 acc = {0.f, 0.f, 0.f, 0.f};
            short8 b0 = *(const short8*)&buf[swzK(n0 + l15, l4 * 16)];
            short8 b1 = *(const short8*)&buf[swzK(n0 + l15, 64 + l4 * 16)];
            acc = __builtin_amdgcn_mfma_f32_16x16x32_bf16(quf[0], b0, acc, 0, 0, 0);
            acc = __builtin_amdgcn_mfma_f32_16x16x32_bf16(quf[1], b1, acc, 0, 0, 0);
            const int col = kt * 64 + n0 + l15;
            #pragma unroll
            for (int r = 0; r < 4; ++r)
                sc[swzS(mT + l4 * 4 + r, col * 2)] = f2b(acc[r]);
        }
        __builtin_amdgcn_s_setprio(0);
        if (doBand) {
            // wave-local RMW region -> no barrier needed
            #pragma unroll
            for (int s = 0; s < 3; ++s) {
                short8 ba = (s == 0) ? bnd00 : ((s == 1) ? bnd10 : bnd20);
                short8 bb = (s == 0) ? bnd01 : ((s == 1) ? bnd11 : bnd21);
                f32x4 acc = {0.f, 0.f, 0.f, 0.f};
                acc = __builtin_amdgcn_mfma_f32_16x16x32_bf16(qvf[0], ba, acc, 0, 0, 0);
                acc = __builtin_amdgcn_mfma_f32_16x16x32_bf16(qvf[1], bb, acc, 0, 0, 0);
                const int tl = t0base + s * 16 + l15;
                #pragma unroll
                for (int r = 0; r < 4; ++r) {
                    const int du = mT + l4 * 4 + r;
                    const int dj = tl - 31 + du;
                    if (dj >= c0 && dj < c0 + 32) {
                        const int ix = swzS(du, (kt * 64 + dj) * 2);
                        sc[ix] = f2b(b2f(sc[ix]) + acc[r]);
                    }
                }
            }
        }
        if (kt < 8) {                          // write-late into other buffer
            unsigned short* nb = stg + (cur ^ 1) * 4096;
            *(u16x8*)&nb[swzK(srow, scolB)] = kna;
            *(u16x8*)&nb[swzK(srow + 32, scolB)] = knb;
        }
        cur ^= 1;
    }

    // PV tile-0 global loads: stay in flight across the barrier + softmax.
    u16x8 va = *(const u16x8*)&VTn[(size_t)srow * 576 + sIdx];
    u16x8 vb = *(const u16x8*)&VTn[(size_t)(srow + 32) * 576 + sIdx];
    barrier_lg();                              // all scores visible

    // ============ softmax (log2 domain; 8 consecutive lanes per row) ========
    {
        const int row = tid >> 3, seg = tid & 7;
        const int q = q0 + row;
        const int qc = q < 560 ? q : 559;
        const unsigned short* mb  = maskBias + (size_t)qc * 576 + seg * 72;
        const unsigned short* pbb = padBias + (size_t)b * 576 + seg * 72;
        float mx = -3.0e38f;
        #pragma unroll
        for (int ci = 0; ci < 9; ++ci) {
            u16x8 sv = *(const u16x8*)&sc[swzS(row, seg * 144 + ci * 16)];
            u16x8 mv = *(const u16x8*)&mb[ci * 8];
            u16x8 pv = *(const u16x8*)&pbb[ci * 8];
            #pragma unroll
            for (int j = 0; j < 8; ++j)
                mx = fmaxf(mx, b2f(sv[j]) + b2f(mv[j]) + b2f(pv[j]));
        }
        mx = fmaxf(mx, __shfl_xor(mx, 1));
        mx = fmaxf(mx, __shfl_xor(mx, 2));
        mx = fmaxf(mx, __shfl_xor(mx, 4));
        float lsum = 0.f;
        #pragma unroll
        for (int ci = 0; ci < 9; ++ci) {
            const int ix = swzS(row, seg * 144 + ci * 16);
            u16x8 sv = *(const u16x8*)&sc[ix];
            u16x8 mv = *(const u16x8*)&mb[ci * 8];
            u16x8 pv = *(const u16x8*)&pbb[ci * 8];
            u16x8 ev;
            #pragma unroll
            for (int j = 0; j < 8; ++j) {
                float e = exp2_fast(b2f(sv[j]) + b2f(mv[j]) + b2f(pv[j]) - mx);
                ev[j] = f2b(e); lsum += e;
            }
            *(u16x8*)&sc[ix] = ev;
        }
        lsum += __shfl_xor(lsum, 1);
        lsum += __shfl_xor(lsum, 2);
        lsum += __shfl_xor(lsum, 4);
        if (seg == 0) rowv[row] = 1.f / lsum;
    }
    // stg free (scores-end barrier passed): write VT tile 0.
    *(u16x8*)&stg[swzK(srow, scolB)] = va;
    *(u16x8*)&stg[swzK(srow + 32, scolB)] = vb;

    // ================= PV (1 drain-free barrier per tile) =================
    f32x4 oacc0 = {0.f, 0.f, 0.f, 0.f}, oacc1 = {0.f, 0.f, 0.f, 0.f};
    cur = 0;
    for (int kt = 0; kt < 9; ++kt) {
        u16x8 vna, vnb;
        if (kt < 8) {
            vna = *(const u16x8*)&VTn[(size_t)srow * 576 + (kt + 1) * 64 + sIdx];
            vnb = *(const u16x8*)&VTn[(size_t)(srow + 32) * 576 + (kt + 1) * 64 + sIdx];
        }
        barrier_lg();                          // buf[cur] + (kt=0) rowv ready
        unsigned short* buf = stg + cur * 4096;
        short8 af0 = *(const short8*)&sc[swzS(mT + l15, kt * 128 + l4 * 16)];
        short8 af1 = *(const short8*)&sc[swzS(mT + l15, kt * 128 + 64 + l4 * 16)];
        __builtin_amdgcn_s_setprio(1);
        {
            short8 b00 = *(const short8*)&buf[swzK(c0 + l15, l4 * 16)];
            short8 b01 = *(const short8*)&buf[swzK(c0 + l15, 64 + l4 * 16)];
            short8 b10 = *(const short8*)&buf[swzK(c0 + 16 + l15, l4 * 16)];
            short8 b11 = *(const short8*)&buf[swzK(c0 + 16 + l15, 64 + l4 * 16)];
            oacc0 = __builtin_amdgcn_mfma_f32_16x16x32_bf16(af0, b00, oacc0, 0, 0, 0);
            oacc0 = __builtin_amdgcn_mfma_f32_16x16x32_bf16(af1, b01, oacc0, 0, 0, 0);
            oacc1 = __builtin_amdgcn_mfma_f32_16x16x32_bf16(af0, b10, oacc1, 0, 0, 0);
            oacc1 = __builtin_amdgcn_mfma_f32_16x16x32_bf16(af1, b11, oacc1, 0, 0, 0);
        }
        __builtin_amdgcn_s_setprio(0);
        if (kt < 8) {
            unsigned short* nb = stg + (cur ^ 1) * 4096;
            *(u16x8*)&nb[swzK(srow, scolB)] = vna;
            *(u16x8*)&nb[swzK(srow + 32, scolB)] = vnb;
        }
        cur ^= 1;
    }

    // ---- epilogue -> attnT bf16
    #pragma unroll
    for (int s = 0; s < 2; ++s) {
        const f32x4 oa = s ? oacc1 : oacc0;
        const int n0 = c0 + s * 16;
        #pragma unroll
        for (int r = 0; r < 4; ++r) {
            const int row = mT + l4 * 4 + r, q = q0 + row;
            if (q < 560)
                attnT[((size_t)q * 16 + b) * 512 + h * 64 + n0 + l15] =
                    f2b(oa[r] * rowv[row]);
        }
    }
}

// ---------------------------------------------------------------------------
extern "C" void kernel_launch(void* const* d_in, const int* in_sizes, int n_in,
                              void* d_out, int out_size, void* d_ws, size_t ws_size,
                              hipStream_t stream) {
    const float* utt     = (const float*)d_in[0];
    const int*   lengths = (const int*)d_in[1];
    const float* rc      = (const float*)d_in[2];
    const float* summ    = (const float*)d_in[3];
    const float* mem     = (const float*)d_in[4];
    const void*  mask    = d_in[5];
    const float* pos_emb = (const float*)d_in[6];
    const float* Wq      = (const float*)d_in[7];
    const float* bq      = (const float*)d_in[8];
    const float* Wkv     = (const float*)d_in[9];
    const float* bkv     = (const float*)d_in[10];
    const float* Wo      = (const float*)d_in[11];
    const float* bo      = (const float*)d_in[12];
    const float* Wpos    = (const float*)d_in[13];
    const float* pbu     = (const float*)d_in[14];
    const float* pbv     = (const float*)d_in[15];

    float* out = (float*)d_out;
    float* out0   = out;
    float* keyOut = out + 4587520;
    float* valOut = out + 9306112;

    int* flags = (int*)d_ws;
    unsigned short* U = (unsigned short*)d_ws + 64;
    unsigned short* utt_bf  = U;
    unsigned short* rc_bf   = utt_bf  + 4194304;
    unsigned short* summ_bf = rc_bf   + 262144;
    unsigned short* mem_bf  = summ_bf + 131072;
    unsigned short* pose_bf = mem_bf  + 262144;
    unsigned short* wq_bf   = pose_bf + 523776;
    unsigned short* wkv_bf  = wq_bf   + 262144;
    unsigned short* wo_bf   = wkv_bf  + 524288;
    unsigned short* wpos_bf = wo_bf   + 262144;
    unsigned short* Qu_bf   = wpos_bf + 262144;
    unsigned short* Qv_bf   = Qu_bf   + 4718592;
    unsigned short* K_bf    = Qv_bf   + 4718592;
    unsigned short* VT_bf   = K_bf    + 4718592;
    unsigned short* posW_bf = VT_bf   + 4718592;
    unsigned short* attnT_bf= posW_bf + 523776;
    unsigned short* maskB   = attnT_bf + 4587520;   // 560*576 = 322560
    unsigned short* padB    = maskB + 322560;       // 16*576  = 9216

    (void)hipMemsetAsync(flags, 0, 2 * sizeof(int), stream);

    conv9_kernel<<<dim3(1024, 10), 256, 0, stream>>>(
        utt, rc, summ, mem, pos_emb, Wq, Wkv, Wo, Wpos,
        utt_bf, rc_bf, summ_bf, mem_bf, pose_bf, wq_bf, wkv_bf, wo_bf, wpos_bf,
        4194304, 262144, 131072, 262144, 523776, 262144, 524288, 262144, 262144,
        (const unsigned int*)mask, (560 * 576) / 4, flags);

    // ---- merged Q + KV + pos GEMMs + maskprep tail: 280+576+32+64 = 952 blk
    GemmJob jq;
    jq.a0 = rc_bf; jq.a1 = utt_bf; jq.a2 = summ_bf;
    jq.rb1 = 512; jq.rb2 = 8704; jq.Mrows = 8960;
    jq.Wt = wq_bf; jq.bias = bq;
    jq.out0 = nullptr; jq.out1 = nullptr;
    jq.auxU = Qu_bf; jq.auxV = Qv_bf;
    jq.pbu = pbu; jq.pbv = pbv;
    jq.mode = 2; jq.clampStart = 0; jq.nBlocks = 4; jq.base = 0;

    GemmJob jkv;
    jkv.a0 = mem_bf; jkv.a1 = rc_bf; jkv.a2 = utt_bf;
    jkv.rb1 = 512; jkv.rb2 = 1024; jkv.Mrows = 9216;
    jkv.Wt = wkv_bf; jkv.bias = bkv;
    jkv.out0 = keyOut; jkv.out1 = valOut;
    jkv.auxU = K_bf; jkv.auxV = VT_bf;
    jkv.pbu = nullptr; jkv.pbv = nullptr;
    jkv.mode = 1; jkv.clampStart = 0; jkv.nBlocks = 8; jkv.base = 280;

    GemmJob jp;
    jp.a0 = pose_bf; jp.a1 = pose_bf; jp.a2 = pose_bf;
    jp.rb1 = 1 << 30; jp.rb2 = 1 << 30; jp.Mrows = 1023;
    jp.Wt = wpos_bf; jp.bias = nullptr;
    jp.out0 = nullptr; jp.out1 = nullptr;
    jp.auxU = posW_bf; jp.auxV = nullptr;
    jp.pbu = nullptr; jp.pbv = nullptr;
    jp.mode = 3; jp.clampStart = 0; jp.nBlocks = 4; jp.base = 856;

    gemm_mfma3<<<952, 256, 0, stream>>>(jq, jkv, jp,
        mask, flags, lengths, maskB, padB, 888);

    attn_mfma_kernel<<<dim3(18, 128), 256, 0, stream>>>(
        Qu_bf, Qv_bf, K_bf, VT_bf, posW_bf, maskB, padB, attnT_bf);

    // ---- out-projection (single job)
    GemmJob jo;
    jo.a0 = attnT_bf; jo.a1 = attnT_bf; jo.a2 = attnT_bf;
    jo.rb1 = 1 << 30; jo.rb2 = 1 << 30; jo.Mrows = 8960;
    jo.Wt = wo_bf; jo.bias = bo;
    jo.out0 = out0; jo.out1 = nullptr;
    jo.auxU = nullptr; jo.auxV = nullptr;
    jo.pbu = nullptr; jo.pbv = nullptr;
    jo.mode = 0; jo.clampStart = 8704; jo.nBlocks = 4; jo.base = 0;

    GemmJob jdummy = jo;
    jdummy.base = 1 << 30;

    gemm_mfma3<<<280, 256, 0, stream>>>(jo, jdummy, jdummy,
        mask, flags, lengths, maskB, padB, 1 << 30);
}

// Round 7
// 295.050 us; speedup vs baseline: 1.2080x; 1.0280x over previous
//
#include <hip/hip_runtime.h>
#include <math.h>

// EmformerAttention MI355X — round 10: GEMM de-regression. maskprep restored
// as its own kernel (r2 config, where the pre-attn GEMM measured <=99us) and
// XCD-aware bijective swizzle on both GEMM grids (888=8x111, 280=8x35) so
// panel-sharing blocks land on one XCD -> L2-hit staging -> shorter vmcnt
// drain. Attention kernel byte-identical to round 9b (control).
// U=512 B=16 D=512 H=8 HD=64 R=32 S=16 M=32 -> Q=560 KV=576 N=128

#define NEG_INF_F (-100000000.0f)
#define SCALE_F   (0.125f)
#define LOG2E_F   (1.44269504f)

typedef short  short8 __attribute__((ext_vector_type(8)));
typedef float  f32x4  __attribute__((ext_vector_type(4)));
typedef unsigned short u16x4 __attribute__((ext_vector_type(4)));
typedef unsigned short u16x8 __attribute__((ext_vector_type(8)));

__device__ __forceinline__ unsigned short f2b(float f) {
    unsigned int u = __builtin_bit_cast(unsigned int, f);
    u = u + 0x7FFFu + ((u >> 16) & 1u);
    return (unsigned short)(u >> 16);
}
__device__ __forceinline__ float b2f(unsigned short h) {
    unsigned int u = ((unsigned int)h) << 16;
    return __builtin_bit_cast(float, u);
}

// 2^x via the native transcendental unit (avoids glibc __exp2f macro clash).
__device__ __forceinline__ float exp2_fast(float x) {
    float r;
    asm("v_exp_f32 %0, %1" : "=v"(r) : "v"(x));
    return r;
}

// Workgroup barrier WITHOUT the vmcnt(0) drain: LDS ops are ordered
// (lgkmcnt), register-destined global loads may stay in flight.
__device__ __forceinline__ void barrier_lg() {
    asm volatile("s_waitcnt lgkmcnt(0)\n\ts_barrier" ::: "memory");
}

// XOR-swizzled LDS indices (colB = byte column; same involution both sides).
__device__ __forceinline__ int swzK(int row, int colB) {   // tile ld = 64 shorts
    return row * 64 + ((colB ^ ((row & 7) << 4)) >> 1);
}
__device__ __forceinline__ int swzS(int row, int colB) {   // sc ld = 576 shorts
    return row * 576 + ((colB ^ ((row & 7) << 4)) >> 1);
}

// ---------------------------------------------------------------------------
// conv9 + mask-dtype detection (blockIdx.y == 9).
__global__ __launch_bounds__(256) void conv9_kernel(
    const float* s0, const float* s1, const float* s2, const float* s3,
    const float* s4, const float* s5, const float* s6, const float* s7,
    const float* s8,
    unsigned short* d0, unsigned short* d1, unsigned short* d2,
    unsigned short* d3, unsigned short* d4, unsigned short* d5,
    unsigned short* d6, unsigned short* d7, unsigned short* d8,
    int n0, int n1, int n2, int n3, int n4, int n5, int n6, int n7, int n8,
    const unsigned int* __restrict__ mask, int nwords, int* __restrict__ flags)
{
    __shared__ int fF, fG;
    const int a = blockIdx.y;
    if (a == 9) {
        if (threadIdx.x == 0) { fF = 0; fG = 0; }
        __syncthreads();
        int lF = 0, lG = 0;
        for (int i = blockIdx.x * 256 + threadIdx.x; i < nwords; i += gridDim.x * 256) {
            unsigned int w = mask[i];
            if (w == 0x3F800000u)      lF = 1;
            else if (w > 1u)           lG = 1;
        }
        if (lF) atomicOr(&fF, 1);
        if (lG) atomicOr(&fG, 1);
        __syncthreads();
        if (threadIdx.x == 0) {
            if (fF) atomicOr(&flags[0], 1);
            if (fG) atomicOr(&flags[1], 1);
        }
        return;
    }
    const float* ss[9] = {s0, s1, s2, s3, s4, s5, s6, s7, s8};
    unsigned short* dd[9] = {d0, d1, d2, d3, d4, d5, d6, d7, d8};
    int nn[9] = {n0, n1, n2, n3, n4, n5, n6, n7, n8};
    const float* s = ss[a];
    unsigned short* d = dd[a];
    const int nq = nn[a] >> 2;
    for (int i = blockIdx.x * 256 + threadIdx.x; i < nq; i += gridDim.x * 256) {
        float4 v = *(const float4*)(s + (size_t)i * 4);
        u16x4 o = {f2b(v.x), f2b(v.y), f2b(v.z), f2b(v.w)};
        *(u16x4*)(d + (size_t)i * 4) = o;
    }
}

// ---------------------------------------------------------------------------
// maskprep: separate small kernel (restored r2 configuration).
__global__ __launch_bounds__(256) void maskprep_kernel(
    const void* __restrict__ maskPtr, const int* __restrict__ flags,
    const int* __restrict__ lengths,
    unsigned short* __restrict__ maskBias, unsigned short* __restrict__ padBias)
{
    const int mode = flags[0] ? 2 : (flags[1] ? 1 : 0);
    const unsigned short NB = f2b(NEG_INF_F);
    for (int i = blockIdx.x * 256 + threadIdx.x; i < 560 * 576; i += gridDim.x * 256) {
        bool m;
        if (mode == 1)      m = ((const unsigned char*)maskPtr)[i] != 0;
        else if (mode == 2) m = ((const float*)maskPtr)[i] != 0.f;
        else                m = ((const int*)maskPtr)[i] != 0;
        maskBias[i] = m ? NB : (unsigned short)0;
    }
    for (int i = blockIdx.x * 256 + threadIdx.x; i < 16 * 576; i += gridDim.x * 256) {
        int b = i / 576, k = i - b * 576;
        padBias[i] = (k >= 64 + lengths[b]) ? NB : (unsigned short)0;
    }
}

// ---------------------------------------------------------------------------
// m97-class bf16 MFMA GEMM (r2 signature) + XCD-aware bijective grid swizzle.
struct GemmJob {
    const unsigned short *a0, *a1, *a2;   // piecewise A rows
    int rb1, rb2, Mrows;
    const unsigned short *Wt;             // [N][512] bf16 (row = out col)
    const float *bias;
    float *out0, *out1;
    unsigned short *auxU, *auxV;
    const float *pbu, *pbv;
    int mode, clampStart;
    int nBlocks;                          // grid blocks along N
    int base;                             // first linear block id of this job
};

__global__ __launch_bounds__(256) void gemm_mfma3(GemmJob J0, GemmJob J1, GemmJob J2)
{
    __shared__ __attribute__((aligned(16))) unsigned short As[128 * 64];
    __shared__ __attribute__((aligned(16))) unsigned short Ws[128 * 64];

    // XCD-aware bijective remap: grid %8 == 0 (888=8x111, 280=8x35).
    // Consecutive LOGICAL ids (sharing A/W panels) land on one XCD's L2.
    const int cpx = gridDim.x >> 3;
    const int bid = (blockIdx.x & 7) * cpx + (blockIdx.x >> 3);

    GemmJob J;
    if (bid >= J2.base)      J = J2;
    else if (bid >= J1.base) J = J1;
    else                     J = J0;
    const int rel = bid - J.base;
    const int bn = (rel % J.nBlocks) * 128;
    const int bm = (rel / J.nBlocks) * 128;

    const int tid = threadIdx.x;
    const int w = tid >> 6, lane = tid & 63;
    const int l15 = lane & 15, l4 = lane >> 4;
    const int wm = (w & 1) * 64, wn = (w >> 1) * 64;

    const int lrow  = lane >> 3;
    const int lslot = lane & 7;
    const int swzS16 = (lslot ^ lrow) * 8;     // pre-swizzled source column

    const unsigned short* srcA[4];
    const unsigned short* srcW[4];
    #pragma unroll
    for (int c = 0; c < 4; ++c) {
        const int row = w * 32 + c * 8 + lrow;
        const int r = bm + row;
        const unsigned short* s;
        if (r < J.rb1)      s = J.a0 + (size_t)r * 512;
        else if (r < J.rb2) s = J.a1 + (size_t)(r - J.rb1) * 512;
        else                s = J.a2 + (size_t)(r - J.rb2) * 512;
        srcA[c] = s + swzS16;
        srcW[c] = J.Wt + (size_t)(bn + row) * 512 + swzS16;
    }

    f32x4 acc[4][4];
    #pragma unroll
    for (int i = 0; i < 4; ++i)
        #pragma unroll
        for (int j = 0; j < 4; ++j) acc[i][j] = (f32x4){0.f, 0.f, 0.f, 0.f};

    #define GFRAG(arr, row, kk) \
        (*(const short8*)&arr[(row) * 64 + ((((kk) * 4 + l4) ^ ((row) & 7)) * 8)])

    for (int kt = 0; kt < 8; ++kt) {
        __syncthreads();
        #pragma unroll
        for (int c = 0; c < 4; ++c) {
            __builtin_amdgcn_global_load_lds(
                (const __attribute__((address_space(1))) unsigned int*)(srcA[c] + kt * 64),
                (__attribute__((address_space(3))) unsigned int*)&As[(w * 32 + c * 8) * 64],
                16, 0, 0);
            __builtin_amdgcn_global_load_lds(
                (const __attribute__((address_space(1))) unsigned int*)(srcW[c] + kt * 64),
                (__attribute__((address_space(3))) unsigned int*)&Ws[(w * 32 + c * 8) * 64],
                16, 0, 0);
        }
        __syncthreads();

        short8 bfr[4][2];
        #pragma unroll
        for (int t = 0; t < 4; ++t) {
            const int r = wn + t * 16 + l15;
            bfr[t][0] = GFRAG(Ws, r, 0);
            bfr[t][1] = GFRAG(Ws, r, 1);
        }
        #pragma unroll
        for (int tm = 0; tm < 4; ++tm) {
            const int r = wm + tm * 16 + l15;
            const short8 a0f = GFRAG(As, r, 0);
            const short8 a1f = GFRAG(As, r, 1);
            #pragma unroll
            for (int tn = 0; tn < 4; ++tn) {
                acc[tm][tn] = __builtin_amdgcn_mfma_f32_16x16x32_bf16(
                    a0f, bfr[tn][0], acc[tm][tn], 0, 0, 0);
                acc[tm][tn] = __builtin_amdgcn_mfma_f32_16x16x32_bf16(
                    a1f, bfr[tn][1], acc[tm][tn], 0, 0, 0);
            }
        }
    }
    #undef GFRAG

    #pragma unroll
    for (int tm = 0; tm < 4; ++tm) {
        #pragma unroll
        for (int tn = 0; tn < 4; ++tn) {
            const int col = bn + wn + tn * 16 + l15;
            const float bv = J.bias ? J.bias[col] : 0.f;
            #pragma unroll
            for (int rr = 0; rr < 4; ++rr) {
                const int row = bm + wm + tm * 16 + l4 * 4 + rr;
                if (row >= J.Mrows) continue;
                float v = acc[tm][tn][rr] + bv;
                if (J.mode == 0) {
                    if (row >= J.clampStart) v = fminf(fmaxf(v, -10.f), 10.f);
                    J.out0[(size_t)row * 512 + col] = v;
                } else if (J.mode == 1) {
                    int bb = row & 15, kv = row >> 4;
                    if (col < 512) {
                        J.out0[(size_t)row * 512 + col] = v;
                        int hh = col >> 6, hd = col & 63;
                        J.auxU[(((size_t)(bb * 8 + hh)) * 576 + kv) * 64 + hd] = f2b(v);
                    } else {
                        J.out1[(size_t)row * 512 + (col - 512)] = v;
                        int cc = col - 512, hh = cc >> 6, hd = cc & 63;
                        J.auxV[(((size_t)(bb * 8 + hh)) * 64 + hd) * 576 + kv] = f2b(v);
                    }
                } else if (J.mode == 2) {
                    // log2-domain: fold SCALE * log2(e) into Qu AND Qv.
                    int q = row >> 4, bb = row & 15, hh = col >> 6, hd = col & 63;
                    size_t base = (((size_t)(bb * 8 + hh)) * 576 + q) * 64 + hd;
                    J.auxU[base] = f2b((v + J.pbu[col]) * (SCALE_F * LOG2E_F));
                    J.auxV[base] = f2b((v + J.pbv[col]) * (SCALE_F * LOG2E_F));
                } else {
                    int hh = col >> 6, hd = col & 63;
                    J.auxU[((size_t)hh * 1023 + row) * 64 + hd] = f2b(v);
                }
            }
        }
    }
}

// ---------------------------------------------------------------------------
// MFMA attention v8 (byte-identical to round 9b — control this round).
__global__ __launch_bounds__(256) void attn_mfma_kernel(
    const unsigned short* __restrict__ Qu_g,  // [n][576][64], *SCALE*log2e
    const unsigned short* __restrict__ Qv_g,  // [n][576][64], *SCALE*log2e
    const unsigned short* __restrict__ K_g,   // [n][576][64]
    const unsigned short* __restrict__ VT_g,  // [n][64][576]
    const unsigned short* __restrict__ P_g,   // [8][1023][64]
    const unsigned short* __restrict__ maskBias, // [560][576] bf16
    const unsigned short* __restrict__ padBias,  // [16][576] bf16
    unsigned short* __restrict__ attnT)       // bf16
{
    __shared__ __attribute__((aligned(16))) unsigned short sc[32 * 576];
    __shared__ __attribute__((aligned(16))) unsigned short stg[2 * 4096];
    __shared__ float rowv[32];

    // XCD-aware remap (2304 = 8 x 288, bijective).
    const int bid = blockIdx.y * 18 + blockIdx.x;
    const int workid = (bid & 7) * 288 + (bid >> 3);
    const int n = workid / 18;
    const int qt = workid - n * 18;

    const int b = n >> 3, h = n & 7;
    const int q0 = qt * 32;
    const int tid = threadIdx.x;
    const int w = tid >> 6, lane = tid & 63;
    const int l15 = lane & 15, l4 = lane >> 4;
    const int mT = (w >> 1) * 16;
    const int c0 = (w & 1) * 32;
    const int t0base = 16 - mT + c0;
    const bool hasBand = (qt >= 1 && qt <= 16);
    const int pbq = 512 - q0;

    const unsigned short* Kn  = K_g  + (size_t)n * 576 * 64;
    const unsigned short* VTn = VT_g + (size_t)n * 64 * 576;
    const unsigned short* Ph  = P_g  + (size_t)h * 1023 * 64;

    const int srow  = tid >> 3;            // 0..31
    const int sIdx  = (tid & 7) * 8;       // short col within row
    const int scolB = sIdx * 2;            // byte col

    // ---- prologue: stage K tile 0 into buf0
    {
        u16x8 a = *(const u16x8*)&Kn[(size_t)srow * 64 + sIdx];
        u16x8 c = *(const u16x8*)&Kn[(size_t)(srow + 32) * 64 + sIdx];
        *(u16x8*)&stg[swzK(srow, scolB)] = a;
        *(u16x8*)&stg[swzK(srow + 32, scolB)] = c;
    }

    short8 quf[2], qvf[2];
    {
        size_t rb = ((size_t)n * 576 + q0 + mT + l15) * 64;
        quf[0] = *(const short8*)&Qu_g[rb + l4 * 8];
        quf[1] = *(const short8*)&Qu_g[rb + 32 + l4 * 8];
        qvf[0] = *(const short8*)&Qv_g[rb + l4 * 8];
        qvf[1] = *(const short8*)&Qv_g[rb + 32 + l4 * 8];
    }

    // ================= scores (1 drain-free barrier per K-tile) ============
    int cur = 0;
    for (int kt = 0; kt < 9; ++kt) {
        // prefetch next K tile into REGISTERS (stays in flight across barrier)
        u16x8 kna, knb;
        if (kt < 8) {
            kna = *(const u16x8*)&Kn[(size_t)((kt + 1) * 64 + srow) * 64 + sIdx];
            knb = *(const u16x8*)&Kn[(size_t)((kt + 1) * 64 + srow + 32) * 64 + sIdx];
        }
        const bool doBand = hasBand && (kt >= 1);
        short8 bnd00, bnd01, bnd10, bnd11, bnd20, bnd21;
        if (doBand) {
            const int pbase = pbq + (kt - 1) * 64 + t0base + l15;
            int p0 = pbase;       p0 = p0 < 0 ? 0 : (p0 > 1022 ? 1022 : p0);
            int p1 = pbase + 16;  p1 = p1 < 0 ? 0 : (p1 > 1022 ? 1022 : p1);
            int p2 = pbase + 32;  p2 = p2 < 0 ? 0 : (p2 > 1022 ? 1022 : p2);
            bnd00 = *(const short8*)&Ph[(size_t)p0 * 64 + l4 * 8];
            bnd01 = *(const short8*)&Ph[(size_t)p0 * 64 + 32 + l4 * 8];
            bnd10 = *(const short8*)&Ph[(size_t)p1 * 64 + l4 * 8];
            bnd11 = *(const short8*)&Ph[(size_t)p1 * 64 + 32 + l4 * 8];
            bnd20 = *(const short8*)&Ph[(size_t)p2 * 64 + l4 * 8];
            bnd21 = *(const short8*)&Ph[(size_t)p2 * 64 + 32 + l4 * 8];
        }
        barrier_lg();                          // buf[cur] ready (no vmcnt drain)
        unsigned short* buf = stg + cur * 4096;
        __builtin_amdgcn_s_setprio(1);
        #pragma unroll
        for (int s = 0; s < 2; ++s) {
            const int n0 = c0 + s * 16;
            f32x4 acc = {0.f, 0.f, 0.f, 0.f};
            short8 b0 = *(const short8*)&buf[swzK(n0 + l15, l4 * 16)];
            short8 b1 = *(const short8*)&buf[swzK(n0 + l15, 64 + l4 * 16)];
            acc = __builtin_amdgcn_mfma_f32_16x16x32_bf16(quf[0], b0, acc, 0, 0, 0);
            acc = __builtin_amdgcn_mfma_f32_16x16x32_bf16(quf[1], b1, acc, 0, 0, 0);
            const int col = kt * 64 + n0 + l15;
            #pragma unroll
            for (int r = 0; r < 4; ++r)
                sc[swzS(mT + l4 * 4 + r, col * 2)] = f2b(acc[r]);
        }
        __builtin_amdgcn_s_setprio(0);
        if (doBand) {
            // wave-local RMW region -> no barrier needed
            #pragma unroll
            for (int s = 0; s < 3; ++s) {
                short8 ba = (s == 0) ? bnd00 : ((s == 1) ? bnd10 : bnd20);
                short8 bb = (s == 0) ? bnd01 : ((s == 1) ? bnd11 : bnd21);
                f32x4 acc = {0.f, 0.f, 0.f, 0.f};
                acc = __builtin_amdgcn_mfma_f32_16x16x32_bf16(qvf[0], ba, acc, 0, 0, 0);
                acc = __builtin_amdgcn_mfma_f32_16x16x32_bf16(qvf[1], bb, acc, 0, 0, 0);
                const int tl = t0base + s * 16 + l15;
                #pragma unroll
                for (int r = 0; r < 4; ++r) {
                    const int du = mT + l4 * 4 + r;
                    const int dj = tl - 31 + du;
                    if (dj >= c0 && dj < c0 + 32) {
                        const int ix = swzS(du, (kt * 64 + dj) * 2);
                        sc[ix] = f2b(b2f(sc[ix]) + acc[r]);
                    }
                }
            }
        }
        if (kt < 8) {                          // write-late into other buffer
            unsigned short* nb = stg + (cur ^ 1) * 4096;
            *(u16x8*)&nb[swzK(srow, scolB)] = kna;
            *(u16x8*)&nb[swzK(srow + 32, scolB)] = knb;
        }
        cur ^= 1;
    }

    // PV tile-0 global loads: stay in flight across the barrier + softmax.
    u16x8 va = *(const u16x8*)&VTn[(size_t)srow * 576 + sIdx];
    u16x8 vb = *(const u16x8*)&VTn[(size_t)(srow + 32) * 576 + sIdx];
    barrier_lg();                              // all scores visible

    // ============ softmax (log2 domain; 8 consecutive lanes per row) ========
    {
        const int row = tid >> 3, seg = tid & 7;
        const int q = q0 + row;
        const int qc = q < 560 ? q : 559;
        const unsigned short* mb  = maskBias + (size_t)qc * 576 + seg * 72;
        const unsigned short* pbb = padBias + (size_t)b * 576 + seg * 72;
        float mx = -3.0e38f;
        #pragma unroll
        for (int ci = 0; ci < 9; ++ci) {
            u16x8 sv = *(const u16x8*)&sc[swzS(row, seg * 144 + ci * 16)];
            u16x8 mv = *(const u16x8*)&mb[ci * 8];
            u16x8 pv = *(const u16x8*)&pbb[ci * 8];
            #pragma unroll
            for (int j = 0; j < 8; ++j)
                mx = fmaxf(mx, b2f(sv[j]) + b2f(mv[j]) + b2f(pv[j]));
        }
        mx = fmaxf(mx, __shfl_xor(mx, 1));
        mx = fmaxf(mx, __shfl_xor(mx, 2));
        mx = fmaxf(mx, __shfl_xor(mx, 4));
        float lsum = 0.f;
        #pragma unroll
        for (int ci = 0; ci < 9; ++ci) {
            const int ix = swzS(row, seg * 144 + ci * 16);
            u16x8 sv = *(const u16x8*)&sc[ix];
            u16x8 mv = *(const u16x8*)&mb[ci * 8];
            u16x8 pv = *(const u16x8*)&pbb[ci * 8];
            u16x8 ev;
            #pragma unroll
            for (int j = 0; j < 8; ++j) {
                float e = exp2_fast(b2f(sv[j]) + b2f(mv[j]) + b2f(pv[j]) - mx);
                ev[j] = f2b(e); lsum += e;
            }
            *(u16x8*)&sc[ix] = ev;
        }
        lsum += __shfl_xor(lsum, 1);
        lsum += __shfl_xor(lsum, 2);
        lsum += __shfl_xor(lsum, 4);
        if (seg == 0) rowv[row] = 1.f / lsum;
    }
    // stg free (scores-end barrier passed): write VT tile 0.
    *(u16x8*)&stg[swzK(srow, scolB)] = va;
    *(u16x8*)&stg[swzK(srow + 32, scolB)] = vb;

    // ================= PV (1 drain-free barrier per tile) =================
    f32x4 oacc0 = {0.f, 0.f, 0.f, 0.f}, oacc1 = {0.f, 0.f, 0.f, 0.f};
    cur = 0;
    for (int kt = 0; kt < 9; ++kt) {
        u16x8 vna, vnb;
        if (kt < 8) {
            vna = *(const u16x8*)&VTn[(size_t)srow * 576 + (kt + 1) * 64 + sIdx];
            vnb = *(const u16x8*)&VTn[(size_t)(srow + 32) * 576 + (kt + 1) * 64 + sIdx];
        }
        barrier_lg();                          // buf[cur] + (kt=0) rowv ready
        unsigned short* buf = stg + cur * 4096;
        short8 af0 = *(const short8*)&sc[swzS(mT + l15, kt * 128 + l4 * 16)];
        short8 af1 = *(const short8*)&sc[swzS(mT + l15, kt * 128 + 64 + l4 * 16)];
        __builtin_amdgcn_s_setprio(1);
        {
            short8 b00 = *(const short8*)&buf[swzK(c0 + l15, l4 * 16)];
            short8 b01 = *(const short8*)&buf[swzK(c0 + l15, 64 + l4 * 16)];
            short8 b10 = *(const short8*)&buf[swzK(c0 + 16 + l15, l4 * 16)];
            short8 b11 = *(const short8*)&buf[swzK(c0 + 16 + l15, 64 + l4 * 16)];
            oacc0 = __builtin_amdgcn_mfma_f32_16x16x32_bf16(af0, b00, oacc0, 0, 0, 0);
            oacc0 = __builtin_amdgcn_mfma_f32_16x16x32_bf16(af1, b01, oacc0, 0, 0, 0);
            oacc1 = __builtin_amdgcn_mfma_f32_16x16x32_bf16(af0, b10, oacc1, 0, 0, 0);
            oacc1 = __builtin_amdgcn_mfma_f32_16x16x32_bf16(af1, b11, oacc1, 0, 0, 0);
        }
        __builtin_amdgcn_s_setprio(0);
        if (kt < 8) {
            unsigned short* nb = stg + (cur ^ 1) * 4096;
            *(u16x8*)&nb[swzK(srow, scolB)] = vna;
            *(u16x8*)&nb[swzK(srow + 32, scolB)] = vnb;
        }
        cur ^= 1;
    }

    // ---- epilogue -> attnT bf16
    #pragma unroll
    for (int s = 0; s < 2; ++s) {
        const f32x4 oa = s ? oacc1 : oacc0;
        const int n0 = c0 + s * 16;
        #pragma unroll
        for (int r = 0; r < 4; ++r) {
            const int row = mT + l4 * 4 + r, q = q0 + row;
            if (q < 560)
                attnT[((size_t)q * 16 + b) * 512 + h * 64 + n0 + l15] =
                    f2b(oa[r] * rowv[row]);
        }
    }
}

// ---------------------------------------------------------------------------
extern "C" void kernel_launch(void* const* d_in, const int* in_sizes, int n_in,
                              void* d_out, int out_size, void* d_ws, size_t ws_size,
                              hipStream_t stream) {
    const float* utt     = (const float*)d_in[0];
    const int*   lengths = (const int*)d_in[1];
    const float* rc      = (const float*)d_in[2];
    const float* summ    = (const float*)d_in[3];
    const float* mem     = (const float*)d_in[4];
    const void*  mask    = d_in[5];
    const float* pos_emb = (const float*)d_in[6];
    const float* Wq      = (const float*)d_in[7];
    const float* bq      = (const float*)d_in[8];
    const float* Wkv     = (const float*)d_in[9];
    const float* bkv     = (const float*)d_in[10];
    const float* Wo      = (const float*)d_in[11];
    const float* bo      = (const float*)d_in[12];
    const float* Wpos    = (const float*)d_in[13];
    const float* pbu     = (const float*)d_in[14];
    const float* pbv     = (const float*)d_in[15];

    float* out = (float*)d_out;
    float* out0   = out;
    float* keyOut = out + 4587520;
    float* valOut = out + 9306112;

    int* flags = (int*)d_ws;
    unsigned short* U = (unsigned short*)d_ws + 64;
    unsigned short* utt_bf  = U;
    unsigned short* rc_bf   = utt_bf  + 4194304;
    unsigned short* summ_bf = rc_bf   + 262144;
    unsigned short* mem_bf  = summ_bf + 131072;
    unsigned short* pose_bf = mem_bf  + 262144;
    unsigned short* wq_bf   = pose_bf + 523776;
    unsigned short* wkv_bf  = wq_bf   + 262144;
    unsigned short* wo_bf   = wkv_bf  + 524288;
    unsigned short* wpos_bf = wo_bf   + 262144;
    unsigned short* Qu_bf   = wpos_bf + 262144;
    unsigned short* Qv_bf   = Qu_bf   + 4718592;
    unsigned short* K_bf    = Qv_bf   + 4718592;
    unsigned short* VT_bf   = K_bf    + 4718592;
    unsigned short* posW_bf = VT_bf   + 4718592;
    unsigned short* attnT_bf= posW_bf + 523776;
    unsigned short* maskB   = attnT_bf + 4587520;   // 560*576 = 322560
    unsigned short* padB    = maskB + 322560;       // 16*576  = 9216

    (void)hipMemsetAsync(flags, 0, 2 * sizeof(int), stream);

    conv9_kernel<<<dim3(1024, 10), 256, 0, stream>>>(
        utt, rc, summ, mem, pos_emb, Wq, Wkv, Wo, Wpos,
        utt_bf, rc_bf, summ_bf, mem_bf, pose_bf, wq_bf, wkv_bf, wo_bf, wpos_bf,
        4194304, 262144, 131072, 262144, 523776, 262144, 524288, 262144, 262144,
        (const unsigned int*)mask, (560 * 576) / 4, flags);

    maskprep_kernel<<<315, 256, 0, stream>>>(mask, flags, lengths, maskB, padB);

    // ---- merged Q + KV + pos projection GEMMs: 280 + 576 + 32 = 888 blocks
    GemmJob jq;
    jq.a0 = rc_bf; jq.a1 = utt_bf; jq.a2 = summ_bf;
    jq.rb1 = 512; jq.rb2 = 8704; jq.Mrows = 8960;
    jq.Wt = wq_bf; jq.bias = bq;
    jq.out0 = nullptr; jq.out1 = nullptr;
    jq.auxU = Qu_bf; jq.auxV = Qv_bf;
    jq.pbu = pbu; jq.pbv = pbv;
    jq.mode = 2; jq.clampStart = 0; jq.nBlocks = 4; jq.base = 0;

    GemmJob jkv;
    jkv.a0 = mem_bf; jkv.a1 = rc_bf; jkv.a2 = utt_bf;
    jkv.rb1 = 512; jkv.rb2 = 1024; jkv.Mrows = 9216;
    jkv.Wt = wkv_bf; jkv.bias = bkv;
    jkv.out0 = keyOut; jkv.out1 = valOut;
    jkv.auxU = K_bf; jkv.auxV = VT_bf;
    jkv.pbu = nullptr; jkv.pbv = nullptr;
    jkv.mode = 1; jkv.clampStart = 0; jkv.nBlocks = 8; jkv.base = 280;

    GemmJob jp;
    jp.a0 = pose_bf; jp.a1 = pose_bf; jp.a2 = pose_bf;
    jp.rb1 = 1 << 30; jp.rb2 = 1 << 30; jp.Mrows = 1023;
    jp.Wt = wpos_bf; jp.bias = nullptr;
    jp.out0 = nullptr; jp.out1 = nullptr;
    jp.auxU = posW_bf; jp.auxV = nullptr;
    jp.pbu = nullptr; jp.pbv = nullptr;
    jp.mode = 3; jp.clampStart = 0; jp.nBlocks = 4; jp.base = 856;

    gemm_mfma3<<<888, 256, 0, stream>>>(jq, jkv, jp);

    attn_mfma_kernel<<<dim3(18, 128), 256, 0, stream>>>(
        Qu_bf, Qv_bf, K_bf, VT_bf, posW_bf, maskB, padB, attnT_bf);

    // ---- out-projection (single job; 280 = 8 x 35, swizzle-compatible)
    GemmJob jo;
    jo.a0 = attnT_bf; jo.a1 = attnT_bf; jo.a2 = attnT_bf;
    jo.rb1 = 1 << 30; jo.rb2 = 1 << 30; jo.Mrows = 8960;
    jo.Wt = wo_bf; jo.bias = bo;
    jo.out0 = out0; jo.out1 = nullptr;
    jo.auxU = nullptr; jo.auxV = nullptr;
    jo.pbu = nullptr; jo.pbv = nullptr;
    jo.mode = 0; jo.clampStart = 8704; jo.nBlocks = 4; jo.base = 0;

    GemmJob jdummy = jo;
    jdummy.base = 1 << 30;

    gemm_mfma3<<<280, 256, 0, stream>>>(jo, jdummy, jdummy);
}